// Round 9
// baseline (412.653 us; speedup 1.0000x reference)
//
#include <hip/hip_runtime.h>
#include <hip/hip_fp16.h>

// ==================== ROUND 9: ATTRIBUTION PROBE (fixed) ====================
// R8's probe tore binMem: duplicate blocks write the same per-bin MULTISET but
// in atomic-order-dependent PERMUTATIONS -> racing writes mixed permutations.
// Fix: every replica owns a private binMem/offTab copy (REP x workspace, 81 MB
// of the 256 MB ws). No shared destinations; per-replica traffic == real run.
// Purpose unchanged: inflate each kernel ~REP x so all three surface in the
// rocprof top-5 with counters. dur_us will be ~8x; that is the price of
// attribution and this round is measurement-only.
// ===========================================================================

#define Bq 16
#define Nq 2048
#define Sq 4096
#define Dq 128
#define VOCABq 50257
#define NNZq 1048576
#define ROWS (Bq * Nq)   // 32768
#define NBIN 512         // bins of 64 rows
#define RPB 64           // rows per bin
#define BTPB 1024        // bin kernel threads
#define BEPT 4           // bin entries per thread
#define ENT (BTPB * BEPT)       // 4096 entries per bin-block
#define NBLK (NNZq / ENT)       // 256 bin blocks
#define PTPB 512         // pool threads
#define NKEY 256         // pool sort keys: 4 token-quarters x 64 rows
#define EBUF 2560        // per-bin entry cap (mean 2048, sd ~45 -> +11 sigma)
#define NQUAD ((VOCABq * Dq) / 4)   // 1,608,224
#define NCASTB ((NQUAD + 255) / 256)
#define REP 8            // probe replication factor

typedef unsigned long long u64;
typedef u64 u64x2 __attribute__((ext_vector_type(2)));
typedef float vfloat4 __attribute__((ext_vector_type(4)));
typedef unsigned short vushort4 __attribute__((ext_vector_type(4)));
typedef unsigned short vushort8 __attribute__((ext_vector_type(8)));

// exclusive prefix over blockDim values (one per thread); NW = waves/block
template <int NW>
__device__ __forceinline__ int scan_block(int val, int t, int* waveSum) {
    int lane = t & 63, wid = t >> 6;
    int vi = val;
    #pragma unroll
    for (int d = 1; d < 64; d <<= 1) {
        int w = __shfl_up(vi, d, 64);
        if (lane >= d) vi += w;
    }
    if (lane == 63) waveSum[wid] = vi;
    __syncthreads();
    if (t == 0) {
        int s = 0;
        #pragma unroll
        for (int w = 0; w < NW; w++) { int x = waveSum[w]; waveSum[w] = s; s += x; }
    }
    __syncthreads();
    return vi - val + waveSum[wid];
}

#define FMA8(e_, v_, A0_, A1_)                                   \
    A0_.x += __half2float(__ushort_as_half(e_[0])) * v_;         \
    A0_.y += __half2float(__ushort_as_half(e_[1])) * v_;         \
    A0_.z += __half2float(__ushort_as_half(e_[2])) * v_;         \
    A0_.w += __half2float(__ushort_as_half(e_[3])) * v_;         \
    A1_.x += __half2float(__ushort_as_half(e_[4])) * v_;         \
    A1_.y += __half2float(__ushort_as_half(e_[5])) * v_;         \
    A1_.z += __half2float(__ushort_as_half(e_[6])) * v_;         \
    A1_.w += __half2float(__ushort_as_half(e_[7])) * v_;

__device__ __forceinline__ void accum_range(
    const u64* ebuf, int k, int s1, int lane16,
    const unsigned short* __restrict__ emb16, vfloat4& A0, vfloat4& A1)
{
    for (; k + 8 <= s1; k += 8) {
        int tk[8]; float vv[8];
        #pragma unroll
        for (int u = 0; u < 8; u++) {
            u64 pk = ebuf[k + u];
            tk[u] = (int)(pk & 0xFFFF);
            vv[u] = __int_as_float((int)(pk >> 32));
        }
        vushort8 e[8];
        #pragma unroll
        for (int u = 0; u < 8; u++)
            e[u] = reinterpret_cast<const vushort8*>(emb16 + (size_t)tk[u] * Dq)[lane16];
        #pragma unroll
        for (int u = 0; u < 8; u++) { FMA8(e[u], vv[u], A0, A1) }
    }
    int rem = s1 - k;          // 0..7, uniform within the 16-lane group
    if (rem > 0) {
        int tk[8]; float vv[8]; vushort8 e[8];
        #pragma unroll
        for (int u = 0; u < 8; u++) if (u < rem) {
            u64 pk = ebuf[k + u];
            tk[u] = (int)(pk & 0xFFFF);
            vv[u] = __int_as_float((int)(pk >> 32));
        }
        #pragma unroll
        for (int u = 0; u < 8; u++) if (u < rem)
            e[u] = reinterpret_cast<const vushort8*>(emb16 + (size_t)tk[u] * Dq)[lane16];
        #pragma unroll
        for (int u = 0; u < 8; u++) if (u < rem) { FMA8(e[u], vv[u], A0, A1) }
    }
}

__device__ __forceinline__ void accum_pair(
    const u64* ebuf, int ka, int s1a, int kb, int s1b, int lane16,
    const unsigned short* __restrict__ emb16,
    vfloat4& A0, vfloat4& A1, vfloat4& B0, vfloat4& B1)
{
    while (ka + 8 <= s1a && kb + 8 <= s1b) {
        int tk[16]; float vv[16];
        #pragma unroll
        for (int u = 0; u < 8; u++) {
            u64 pa = ebuf[ka + u];
            tk[u]     = (int)(pa & 0xFFFF);
            vv[u]     = __int_as_float((int)(pa >> 32));
            u64 pb = ebuf[kb + u];
            tk[u + 8] = (int)(pb & 0xFFFF);
            vv[u + 8] = __int_as_float((int)(pb >> 32));
        }
        vushort8 e[16];
        #pragma unroll
        for (int u = 0; u < 16; u++)
            e[u] = reinterpret_cast<const vushort8*>(emb16 + (size_t)tk[u] * Dq)[lane16];
        #pragma unroll
        for (int u = 0; u < 8; u++) { FMA8(e[u], vv[u], A0, A1) }
        #pragma unroll
        for (int u = 0; u < 8; u++) { FMA8(e[u + 8], vv[u + 8], B0, B1) }
        ka += 8; kb += 8;
    }
    accum_range(ebuf, ka, s1a, lane16, emb16, A0, A1);
    accum_range(ebuf, kb, s1b, lane16, emb16, B0, B1);
}

// ---------- Pass 0: cast (grid x REP; byte-identical duplicates, benign) ----------
__global__ __launch_bounds__(256) void cast_kernel(
    const float* __restrict__ emb, unsigned short* __restrict__ emb16)
{
    int i = (blockIdx.x % NCASTB) * 256 + threadIdx.x;
    if (i >= NQUAD) return;
    vfloat4 f = reinterpret_cast<const vfloat4*>(emb)[i];
    vushort4 h;
    h.x = __half_as_ushort(__float2half_rn(f.x));
    h.y = __half_as_ushort(__float2half_rn(f.y));
    h.z = __half_as_ushort(__float2half_rn(f.z));
    h.w = __half_as_ushort(__float2half_rn(f.w));
    __builtin_nontemporal_store(h, reinterpret_cast<vushort4*>(emb16) + i);
}

// ---------- Pass A: bin (replica r -> private binMem/offTab copy r) ----------
__global__ __launch_bounds__(BTPB) void bin_kernel(
    const int* __restrict__ subnode_ids,
    const int* __restrict__ mb,
    const int* __restrict__ mn,
    const int* __restrict__ ms,
    const float* __restrict__ mv,
    u64* __restrict__ binMem,              // [REP][NBLK][ENT]
    unsigned* __restrict__ offTab)         // [REP][NBLK][NBIN] off | cnt<<16
{
    __shared__ int hist[NBIN];
    __shared__ int lstart[NBIN];
    __shared__ int waveSum[BTPB / 64];
    __shared__ u64 spk[ENT] __attribute__((aligned(16)));

    int t   = threadIdx.x;
    int rep = blockIdx.x / NBLK;           // PROBE: private output copy per replica
    int blk = blockIdx.x % NBLK;

    if (t < NBIN) hist[t] = 0;
    __syncthreads();

    int base = blk * ENT;
    int g[BEPT], rank[BEPT];
    u64 pk[BEPT];
    #pragma unroll
    for (int k = 0; k < BEPT; k++) {
        int i   = base + k * BTPB + t;
        int b   = __builtin_nontemporal_load(mb + i);
        int row = b * Nq + __builtin_nontemporal_load(mn + i);
        int s   = __builtin_nontemporal_load(ms + i);
        float v = __builtin_nontemporal_load(mv + i);
        int tok = subnode_ids[b * Sq + s];
        g[k]  = row >> 6;
        pk[k] = ((u64)(unsigned)__float_as_int(v) << 32)
              | ((u64)(row & 63) << 16)
              | (unsigned)tok;
        rank[k] = atomicAdd(&hist[g[k]], 1);
    }
    __syncthreads();

    int cnt = (t < NBIN) ? hist[t] : 0;
    int ex  = scan_block<BTPB / 64>(cnt, t, waveSum);
    if (t < NBIN) {
        lstart[t] = ex;
        offTab[((size_t)rep * NBLK + blk) * NBIN + t] = (unsigned)ex | ((unsigned)cnt << 16);
    }
    __syncthreads();

    #pragma unroll
    for (int k = 0; k < BEPT; k++)
        spk[lstart[g[k]] + rank[k]] = pk[k];
    __syncthreads();

    const u64x2* s2 = reinterpret_cast<const u64x2*>(spk);
    u64x2* d2 = reinterpret_cast<u64x2*>(binMem + ((size_t)rep * NBLK + blk) * ENT);
    #pragma unroll
    for (int p = t; p < ENT / 2; p += BTPB) d2[p] = s2[p];
}

// ---------- Pass B: pool (replica r reads copy r; output writes identical) ----------
__global__ __launch_bounds__(PTPB) void pool_kernel(
    const unsigned short* __restrict__ emb16,
    const u64* __restrict__ binMem,        // [REP][NBLK][ENT]
    const unsigned* __restrict__ offTab,   // [REP][NBLK][NBIN]
    float* __restrict__ out)
{
    __shared__ u64 spk[EBUF] __attribute__((aligned(16)));
    __shared__ u64 ebuf[EBUF];
    __shared__ int waveSum[PTPB / 64];
    __shared__ int khist[NKEY];
    __shared__ int kstart[NKEY + 1];
    __shared__ int kcursor[NKEY];
    __shared__ int nTot;

    int t   = threadIdx.x;
    int rep = blockIdx.x / NBIN;           // PROBE: read private copy rep
    int bin = blockIdx.x % NBIN;

    int slice = t >> 1, half = t & 1;
    unsigned m = offTab[((size_t)rep * NBLK + slice) * NBIN + bin];
    int soff = (int)(m & 0xFFFFu);
    int c    = (int)(m >> 16);
    int c0   = (c + 1) >> 1;
    int myoff = soff + (half ? c0 : 0);
    int myc   = half ? (c - c0) : c0;
    int db = scan_block<PTPB / 64>(myc, t, waveSum);
    if (t == PTPB - 1) nTot = db + myc;
    if (db >= EBUF) myc = 0;
    else if (db + myc > EBUF) myc = EBUF - db;

    {
        const u64* src = binMem + ((size_t)rep * NBLK + slice) * ENT + myoff;
        for (int i = 0; i < myc; i++) spk[db + i] = src[i];
    }
    if (t < NKEY) khist[t] = 0;
    __syncthreads();

    int n = nTot < EBUF ? nTot : EBUF;

    for (int e = t; e < n; e += PTPB) {
        u64 p = spk[e];
        int key = (((int)(p & 0xFFFF)) >> 14 << 6) | ((int)(p >> 16) & 63);
        atomicAdd(&khist[key], 1);
    }
    __syncthreads();

    int kval = (t < NKEY) ? khist[t] : 0;
    int kex  = scan_block<PTPB / 64>(kval, t, waveSum);
    if (t < NKEY) {
        kstart[t]  = kex;
        kcursor[t] = kex;
        if (t == NKEY - 1) kstart[NKEY] = kex + kval;
    }
    __syncthreads();

    for (int e = t; e < n; e += PTPB) {
        u64 p = spk[e];
        int key = (((int)(p & 0xFFFF)) >> 14 << 6) | ((int)(p >> 16) & 63);
        int pos = atomicAdd(&kcursor[key], 1);
        ebuf[pos] = p;
    }
    __syncthreads();

    int g2     = t >> 4;
    int lane16 = t & 15;
    int r0 = g2, r1 = g2 + 32;
    vfloat4 a0 = {0.f,0.f,0.f,0.f}, a1 = {0.f,0.f,0.f,0.f};
    vfloat4 b0 = {0.f,0.f,0.f,0.f}, b1 = {0.f,0.f,0.f,0.f};
    #pragma unroll
    for (int q = 0; q < 4; q++) {
        accum_pair(ebuf,
                   kstart[q * 64 + r0], kstart[q * 64 + r0 + 1],
                   kstart[q * 64 + r1], kstart[q * 64 + r1 + 1],
                   lane16, emb16, a0, a1, b0, b1);
    }

    float* orow0 = out + ((size_t)bin * RPB + r0) * Dq + lane16 * 8;
    float* orow1 = out + ((size_t)bin * RPB + r1) * Dq + lane16 * 8;
    __builtin_nontemporal_store(a0, reinterpret_cast<vfloat4*>(orow0));
    __builtin_nontemporal_store(a1, reinterpret_cast<vfloat4*>(orow0) + 1);
    __builtin_nontemporal_store(b0, reinterpret_cast<vfloat4*>(orow1));
    __builtin_nontemporal_store(b1, reinterpret_cast<vfloat4*>(orow1) + 1);
}

extern "C" void kernel_launch(void* const* d_in, const int* in_sizes, int n_in,
                              void* d_out, int out_size, void* d_ws, size_t ws_size,
                              hipStream_t stream) {
    const int*   subnode_ids  = (const int*)d_in[0];
    const int*   mask_batch   = (const int*)d_in[1];
    const int*   mask_node    = (const int*)d_in[2];
    const int*   mask_subnode = (const int*)d_in[3];
    const float* mask_values  = (const float*)d_in[4];
    const float* emb_table    = (const float*)d_in[5];
    float*       out          = (float*)d_out;

    // ws: emb16[12.86 MB] | binMem[REP][NBLK][ENT] 64 MB | offTab[REP][...] 4 MB
    unsigned short* emb16 = (unsigned short*)d_ws;
    u64* binMem = (u64*)(emb16 + (size_t)VOCABq * Dq + 64 /*align pad*/);
    unsigned* offTab = (unsigned*)(binMem + (size_t)REP * NBLK * ENT);

    // PROBE: each kernel at REP x grid so it surfaces in rocprof top-5
    cast_kernel<<<NCASTB * REP, 256, 0, stream>>>(emb_table, emb16);
    bin_kernel<<<NBLK * REP, BTPB, 0, stream>>>(
        subnode_ids, mask_batch, mask_node, mask_subnode, mask_values,
        binMem, offTab);
    pool_kernel<<<NBIN * REP, PTPB, 0, stream>>>(emb16, binMem, offTab, out);
}

// Round 10
// 207.783 us; speedup vs baseline: 1.9860x; 1.9860x over previous
//
#include <hip/hip_runtime.h>
#include <hip/hip_fp16.h>

#define Bq 16
#define Nq 2048
#define Sq 4096
#define Dq 128
#define VOCABq 50257
#define NNZq 1048576
#define ROWS (Bq * Nq)   // 32768
#define NBIN 512         // bins of 64 rows
#define RPB 64           // rows per bin
#define BTPB 1024        // bin kernel threads
#define BEPT 4           // bin entries per thread
#define ENT (BTPB * BEPT)       // 4096 entries per bin-block
#define NBLK (NNZq / ENT)       // 256 bin blocks
#define NKEY2 2048       // bin sort keys: bin(9b) x token-quarter(2b)
#define PTPB 512         // pool threads
#define QCAP 768         // per-(bin,quarter) cap (mean 512, sd ~23 -> +11 sigma)
#define NQUAD ((VOCABq * Dq) / 4)   // 1,608,224

typedef unsigned long long u64;
typedef u64 u64x2 __attribute__((ext_vector_type(2)));
typedef float vfloat4 __attribute__((ext_vector_type(4)));
typedef unsigned vuint4 __attribute__((ext_vector_type(4)));
typedef unsigned short vushort4 __attribute__((ext_vector_type(4)));
typedef unsigned short vushort8 __attribute__((ext_vector_type(8)));

// exclusive prefix over blockDim values (one per thread); NW = waves/block
template <int NW>
__device__ __forceinline__ int scan_block(int val, int t, int* waveSum) {
    int lane = t & 63, wid = t >> 6;
    int vi = val;
    #pragma unroll
    for (int d = 1; d < 64; d <<= 1) {
        int w = __shfl_up(vi, d, 64);
        if (lane >= d) vi += w;
    }
    if (lane == 63) waveSum[wid] = vi;
    __syncthreads();
    if (t == 0) {
        int s = 0;
        #pragma unroll
        for (int w = 0; w < NW; w++) { int x = waveSum[w]; waveSum[w] = s; s += x; }
    }
    __syncthreads();
    return vi - val + waveSum[wid];
}

#define FMA8(e_, v_, A0_, A1_)                                   \
    A0_.x += __half2float(__ushort_as_half(e_[0])) * v_;         \
    A0_.y += __half2float(__ushort_as_half(e_[1])) * v_;         \
    A0_.z += __half2float(__ushort_as_half(e_[2])) * v_;         \
    A0_.w += __half2float(__ushort_as_half(e_[3])) * v_;         \
    A1_.x += __half2float(__ushort_as_half(e_[4])) * v_;         \
    A1_.y += __half2float(__ushort_as_half(e_[5])) * v_;         \
    A1_.z += __half2float(__ushort_as_half(e_[6])) * v_;         \
    A1_.w += __half2float(__ushort_as_half(e_[7])) * v_;

// accumulate ebuf[k..s1): 8-deep chunks + one predicated 8-chunk tail.
// Shallow on purpose: R9 showed the compiler caps pipeline depth (VGPR 44);
// we spend the budget on occupancy (TLP) instead.
__device__ __forceinline__ void accum_range(
    const u64* ebuf, int k, int s1, int lane16,
    const unsigned short* __restrict__ emb16, vfloat4& A0, vfloat4& A1)
{
    for (; k + 8 <= s1; k += 8) {
        int tk[8]; float vv[8];
        #pragma unroll
        for (int u = 0; u < 8; u++) {
            u64 pk = ebuf[k + u];          // same addr within 16-lane group -> broadcast
            tk[u] = (int)(pk & 0xFFFF);
            vv[u] = __int_as_float((int)(pk >> 32));
        }
        vushort8 e[8];
        #pragma unroll
        for (int u = 0; u < 8; u++)
            e[u] = reinterpret_cast<const vushort8*>(emb16 + (size_t)tk[u] * Dq)[lane16];
        #pragma unroll
        for (int u = 0; u < 8; u++) { FMA8(e[u], vv[u], A0, A1) }
    }
    int rem = s1 - k;          // 0..7, uniform within the 16-lane group
    if (rem > 0) {
        int tk[8]; float vv[8]; vushort8 e[8];
        #pragma unroll
        for (int u = 0; u < 8; u++) if (u < rem) {
            u64 pk = ebuf[k + u];
            tk[u] = (int)(pk & 0xFFFF);
            vv[u] = __int_as_float((int)(pk >> 32));
        }
        #pragma unroll
        for (int u = 0; u < 8; u++) if (u < rem)
            e[u] = reinterpret_cast<const vushort8*>(emb16 + (size_t)tk[u] * Dq)[lane16];
        #pragma unroll
        for (int u = 0; u < 8; u++) if (u < rem) { FMA8(e[u], vv[u], A0, A1) }
    }
}

// ---------- Pass 0: cast emb table fp32 -> fp16 (rows 512B -> 256B) ----------
__global__ __launch_bounds__(256) void cast_kernel(
    const float* __restrict__ emb, unsigned short* __restrict__ emb16)
{
    int i = blockIdx.x * 256 + threadIdx.x;
    if (i >= NQUAD) return;
    vfloat4 f = reinterpret_cast<const vfloat4*>(emb)[i];
    vushort4 h;
    h.x = __half_as_ushort(__float2half_rn(f.x));
    h.y = __half_as_ushort(__float2half_rn(f.y));
    h.z = __half_as_ushort(__float2half_rn(f.z));
    h.w = __half_as_ushort(__float2half_rn(f.w));
    __builtin_nontemporal_store(h, reinterpret_cast<vushort4*>(emb16) + i);
}

// ---------- Pass A: per-block (bin,quarter) sort -> private segment ----------
// Key = (row>>6)<<2 | tok>>14 (2048 keys). Pool then only needs a 64-key row
// sort per quarter -> tiny LDS -> 4x pool occupancy. No global atomics,
// coalesced blob stores, packed off|cnt<<16 per (block,key).
__global__ __launch_bounds__(BTPB) void bin_kernel(
    const int* __restrict__ subnode_ids,   // [B,S]
    const int* __restrict__ mb,            // [NNZ]
    const int* __restrict__ mn,            // [NNZ]
    const int* __restrict__ ms,            // [NNZ]
    const float* __restrict__ mv,          // [NNZ]
    u64* __restrict__ binMem,              // [NBLK][ENT] sorted blobs
    unsigned* __restrict__ offTab)         // [NBLK][NKEY2] off | cnt<<16
{
    __shared__ int hist[NKEY2];            // 8 KB
    __shared__ int lstart[NKEY2];          // 8 KB
    __shared__ int waveSum[BTPB / 64];
    __shared__ u64 spk[ENT] __attribute__((aligned(16)));   // 32 KB

    int t   = threadIdx.x;
    int blk = blockIdx.x;

    hist[2 * t]     = 0;
    hist[2 * t + 1] = 0;
    __syncthreads();

    int base = blk * ENT;
    int g[BEPT], rank[BEPT];
    u64 pk[BEPT];
    #pragma unroll
    for (int k = 0; k < BEPT; k++) {       // coalesced NT index loads + L2 token gather
        int i   = base + k * BTPB + t;
        int b   = __builtin_nontemporal_load(mb + i);
        int row = b * Nq + __builtin_nontemporal_load(mn + i);
        int s   = __builtin_nontemporal_load(ms + i);
        float v = __builtin_nontemporal_load(mv + i);
        int tok = subnode_ids[b * Sq + s];
        g[k]  = ((row >> 6) << 2) | (tok >> 14);   // (bin, token-quarter)
        pk[k] = ((u64)(unsigned)__float_as_int(v) << 32)
              | ((u64)(row & 63) << 16)
              | (unsigned)tok;             // tok < 65536 fits 16 bits
        rank[k] = atomicAdd(&hist[g[k]], 1);
    }
    __syncthreads();

    // scan over 2048 keys: thread t owns keys 2t, 2t+1
    int v0 = hist[2 * t], v1 = hist[2 * t + 1];
    int ex = scan_block<BTPB / 64>(v0 + v1, t, waveSum);
    lstart[2 * t]     = ex;
    lstart[2 * t + 1] = ex + v0;
    offTab[(size_t)blk * NKEY2 + 2 * t]     = (unsigned)ex        | ((unsigned)v0 << 16);
    offTab[(size_t)blk * NKEY2 + 2 * t + 1] = (unsigned)(ex + v0) | ((unsigned)v1 << 16);
    __syncthreads();

    #pragma unroll
    for (int k = 0; k < BEPT; k++)
        spk[lstart[g[k]] + rank[k]] = pk[k];
    __syncthreads();

    // contiguous vectorized blob write-out (16B stores)
    const u64x2* s2 = reinterpret_cast<const u64x2*>(spk);
    u64x2* d2 = reinterpret_cast<u64x2*>(binMem + (size_t)blk * ENT);
    #pragma unroll
    for (int p = t; p < ENT / 2; p += BTPB) d2[p] = s2[p];
}

// ---------- Pass B: per-quarter {stage -> 64-key row sort -> gather} ----------
// Block b = bin b. LDS ~13 KB (spkQ/ebufQ 6 KB each) -> 4 blocks/CU at 512
// threads = 100% occupancy (vs R9-measured 42%). Per quarter: thread t<256
// copies producer-block t's (bin,q) slice into spkQ; 64-key row histogram +
// wave0 scan + scatter into ebufQ; 32 groups x 16 lanes, group g accumulates
// rows g and g+32 from contiguous ranges. Accumulators persist across the 4
// quarters; one NT 512B store per row at the end.
__global__ __launch_bounds__(PTPB, 8) void pool_kernel(
    const unsigned short* __restrict__ emb16,  // [VOCAB,D] fp16
    const u64* __restrict__ binMem,            // [NBLK][ENT]
    const unsigned* __restrict__ offTab,       // [NBLK][NKEY2] off | cnt<<16
    float* __restrict__ out)                   // [ROWS,D]
{
    __shared__ u64 spkQ[QCAP] __attribute__((aligned(16)));  // 6 KB staged
    __shared__ u64 ebufQ[QCAP];            // 6 KB row-sorted
    __shared__ int waveSum[PTPB / 64];
    __shared__ int khist[64];
    __shared__ int kstart[65];
    __shared__ int kcursor[64];
    __shared__ int nTot;

    int t   = threadIdx.x;
    int bin = blockIdx.x;

    // thread t<256 owns producer block t's 4 quarter-slices (one dwordx4)
    vuint4 mm = {0, 0, 0, 0};
    if (t < NBLK)
        mm = *reinterpret_cast<const vuint4*>(offTab + (size_t)t * NKEY2 + bin * 4);

    int g2     = t >> 4;       // 0..31
    int lane16 = t & 15;
    vfloat4 a0 = {0.f,0.f,0.f,0.f}, a1 = {0.f,0.f,0.f,0.f};   // row g2
    vfloat4 b0 = {0.f,0.f,0.f,0.f}, b1 = {0.f,0.f,0.f,0.f};   // row g2+32

    #pragma unroll
    for (int q = 0; q < 4; q++) {
        unsigned m = (q == 0) ? mm.x : (q == 1) ? mm.y : (q == 2) ? mm.z : mm.w;
        int soff = (int)(m & 0xFFFFu);
        int c    = (t < NBLK) ? (int)(m >> 16) : 0;
        int db   = scan_block<PTPB / 64>(c, t, waveSum);
        if (t == PTPB - 1) nTot = db + c;
        if (db >= QCAP) c = 0;
        else if (db + c > QCAP) c = QCAP - db;   // paranoia clamp (never expected)
        if (t < 64) khist[t] = 0;
        __syncthreads();
        int n = nTot < QCAP ? nTot : QCAP;

        // stage this quarter's slices into spkQ
        if (c > 0) {
            const u64* src = binMem + (size_t)t * ENT + soff;
            for (int i = 0; i < c; i++) spkQ[db + i] = src[i];
        }
        __syncthreads();

        // 64-key row histogram
        for (int e = t; e < n; e += PTPB)
            atomicAdd(&khist[(int)(spkQ[e] >> 16) & 63], 1);
        __syncthreads();

        // wave0 inclusive scan over 64 keys
        if (t < 64) {
            int v  = khist[t];
            int vi = v;
            #pragma unroll
            for (int d = 1; d < 64; d <<= 1) {
                int w = __shfl_up(vi, d, 64);
                if (t >= d) vi += w;
            }
            kstart[t + 1] = vi;
            kcursor[t]    = vi - v;
            if (t == 0) kstart[0] = 0;
        }
        __syncthreads();

        // scatter into row-sorted ebufQ
        for (int e = t; e < n; e += PTPB) {
            u64 p = spkQ[e];
            int pos = atomicAdd(&kcursor[(int)(p >> 16) & 63], 1);
            ebufQ[pos] = p;
        }
        __syncthreads();

        // gather-accumulate rows g2 and g2+32 for this quarter
        accum_range(ebufQ, kstart[g2],      kstart[g2 + 1],  lane16, emb16, a0, a1);
        accum_range(ebufQ, kstart[g2 + 32], kstart[g2 + 33], lane16, emb16, b0, b1);
        // no trailing barrier needed: next iteration's scan_block syncs before
        // any shared state read by the gather (kstart/ebufQ) is overwritten
    }

    float* orow0 = out + ((size_t)bin * RPB + g2) * Dq + lane16 * 8;
    float* orow1 = out + ((size_t)bin * RPB + g2 + 32) * Dq + lane16 * 8;
    __builtin_nontemporal_store(a0, reinterpret_cast<vfloat4*>(orow0));
    __builtin_nontemporal_store(a1, reinterpret_cast<vfloat4*>(orow0) + 1);
    __builtin_nontemporal_store(b0, reinterpret_cast<vfloat4*>(orow1));
    __builtin_nontemporal_store(b1, reinterpret_cast<vfloat4*>(orow1) + 1);
}

extern "C" void kernel_launch(void* const* d_in, const int* in_sizes, int n_in,
                              void* d_out, int out_size, void* d_ws, size_t ws_size,
                              hipStream_t stream) {
    const int*   subnode_ids  = (const int*)d_in[0];
    const int*   mask_batch   = (const int*)d_in[1];
    const int*   mask_node    = (const int*)d_in[2];
    const int*   mask_subnode = (const int*)d_in[3];
    const float* mask_values  = (const float*)d_in[4];
    const float* emb_table    = (const float*)d_in[5];
    float*       out          = (float*)d_out;

    // ws layout: emb16[VOCAB*D halves, 12.86 MB] | binMem[NBLK*ENT u64, 8 MB]
    //          | offTab[NBLK*NKEY2 u32, 2 MB]
    unsigned short* emb16 = (unsigned short*)d_ws;
    u64* binMem = (u64*)(emb16 + (size_t)VOCABq * Dq + 64 /*align pad*/);
    unsigned* offTab = (unsigned*)(binMem + (size_t)NBLK * ENT);

    cast_kernel<<<(NQUAD + 255) / 256, 256, 0, stream>>>(emb_table, emb16);
    bin_kernel<<<NBLK, BTPB, 0, stream>>>(
        subnode_ids, mask_batch, mask_node, mask_subnode, mask_values,
        binMem, offTab);
    pool_kernel<<<NBIN, PTPB, 0, stream>>>(emb16, binMem, offTab, out);
}